// Round 12
// baseline (2596.914 us; speedup 1.0000x reference)
//
#include <hip/hip_runtime.h>
#include <hip/hip_bf16.h>
#include <cstdint>

#define B_   4
#define N_   8192
#define NP_  2048
#define NS_  32
#define CIN_ 64
#define M_   (B_*NP_*NS_)   // 262144 rows
#define EPS_ 1e-5f
#define R2_  0.01f          // d2 <= 0.01f  <=>  d2 < float64(0.1*0.1)

typedef unsigned long long ull;
typedef float v2f __attribute__((ext_vector_type(2)));

// ---------------- feature transpose: (B,CIN,N) f32 -> (B,N,CIN) bf16 ----------------
__global__ __launch_bounds__(256) void transpose_kernel(const float* __restrict__ feat,
                                                        __hip_bfloat16* __restrict__ featT)
{
    __shared__ float tile[64][65];
    const int b  = blockIdx.y;
    const int j0 = blockIdx.x * 64;
    const int tx = threadIdx.x & 63, ty = threadIdx.x >> 6;
    for (int cc = ty; cc < 64; cc += 4)
        tile[tx][cc] = feat[((size_t)(b*CIN_ + cc))*N_ + j0 + tx];
    __syncthreads();
    for (int cc = ty; cc < 64; cc += 4)
        featT[((size_t)(b*N_ + j0 + cc))*64 + tx] = __float2bfloat16(tile[cc][tx]);
}

// f32 max with DPP neighbor (invalid lanes keep old value -> identity under max)
template<int CTRL>
__device__ __forceinline__ float dppmaxf(float v)
{
    int o = __builtin_amdgcn_update_dpp(__float_as_int(v), __float_as_int(v), CTRL, 0xF, 0xF, false);
    return fmaxf(v, __int_as_float(o));
}

// ---- FPS: 512 thr x 16 pts, ONE barrier/iter via monotonic u64 key atomic, no global stores ----
__global__ __launch_bounds__(512) void fps_kernel(const float* __restrict__ xyz,
    float* __restrict__ new_xyzf, float* __restrict__ out)
{
#pragma clang fp contract(off)
    const int b = blockIdx.x;
    const int t = threadIdx.x;
    const float* X = xyz + (size_t)b * N_ * 3;

    __shared__ float4 xyz4[N_];            // 128 KB coords (one b128 read per winner)
    __shared__ unsigned short widxs[NP_];  // 4 KB winner indices (epilogue writes them out)
    __shared__ ull slot;                   // monotonic key {it<<45 | dist<<13 | (8191-idx)}

    for (int p = t; p < N_; p += 512)
        xyz4[p] = make_float4(X[p*3+0], X[p*3+1], X[p*3+2], 0.f);
    if (t == 0) { slot = 0ull; widxs[0] = 0; }

    // 16 points per thread, strided pairs (2g*512+t, (2g+1)*512+t)  [R7-exact math]
    v2f px[8], py[8], pz[8], dst[8];
#pragma unroll
    for (int g = 0; g < 8; ++g) {
        const int p0 = (2*g)*512 + t, p1 = (2*g+1)*512 + t;
        px[g] = (v2f){X[p0*3+0], X[p1*3+0]};
        py[g] = (v2f){X[p0*3+1], X[p1*3+1]};
        pz[g] = (v2f){X[p0*3+2], X[p1*3+2]};
        dst[g] = (v2f){1e10f, 1e10f};
    }
    float cx = X[0], cy = X[1], cz = X[2];   // first sampled point = index 0
    __syncthreads();                          // staging + slot init visible

    for (int it = 1; it < NP_; ++it) {
        // phase 1: distance update + per-thread best VALUE only (R7-exact op order)
        float bestv = -1.0f;
        const v2f c0 = (v2f){cx, cx}, c1 = (v2f){cy, cy}, c2 = (v2f){cz, cz};
#pragma unroll
        for (int g = 0; g < 8; ++g) {
            v2f dx = px[g] - c0, dy = py[g] - c1, dz = pz[g] - c2;
            v2f dd = dx*dx;          // contract(off): exact numpy op order per component
            dd = dd + dy*dy;
            dd = dd + dz*dz;
            v2f nd;
            nd.x = fminf(dst[g].x, dd.x);
            nd.y = fminf(dst[g].y, dd.y);
            dst[g] = nd;
            bestv = fmaxf(bestv, nd.x);
            bestv = fmaxf(bestv, nd.y);
        }
        // wave value-max via DPP -> lane63 -> broadcast
        float wm = bestv;
        wm = dppmaxf<0x111>(wm);
        wm = dppmaxf<0x112>(wm);
        wm = dppmaxf<0x114>(wm);
        wm = dppmaxf<0x118>(wm);
        wm = dppmaxf<0x142>(wm);
        wm = dppmaxf<0x143>(wm);
        const float wm_b = __int_as_float(__builtin_amdgcn_readlane(__float_as_int(wm), 63));
        // tying thread(s): rescan registers for smallest local idx, then one u64 LDS atomic
        if (bestv == wm_b) {
            int idx = 0;
#pragma unroll
            for (int g = 7; g >= 0; --g) {     // descending: last assignment = smallest index
                if (dst[g].y == wm_b) idx = (2*g+1)*512 + t;
                if (dst[g].x == wm_b) idx = (2*g)*512 + t;
            }
            const ull key = ((ull)(unsigned)it << 45)
                          | ((ull)__float_as_uint(wm_b) << 13)
                          | (ull)(unsigned)(8191 - idx);
            atomicMax(&slot, key);             // it-monotonic: stale keys always lose
        }
        __syncthreads();                       // the ONLY barrier per iteration
        const ull k = slot;
        const int widx = 8191 - (int)(k & 0x1fffull);
        if (t == 0) widxs[it] = (unsigned short)widx;
        const float4 c = xyz4[widx];           // single b128 broadcast read
        cx = c.x; cy = c.y; cz = c.z;
    }
    __syncthreads();                           // widxs complete
    for (int i = t; i < NP_; i += 512) {       // epilogue: write outputs once
        const float4 c = xyz4[widxs[i]];
        const size_t o3 = ((size_t)(b*NP_ + i)) * 3;
        new_xyzf[o3] = c.x; new_xyzf[o3+1] = c.y; new_xyzf[o3+2] = c.z;
        out[o3] = c.x; out[o3+1] = c.y; out[o3+2] = c.z;
    }
}

// ---------------- ball query: one wave per center ----------------
__global__ __launch_bounds__(256) void ball_kernel(const float* __restrict__ xyz,
    const float* __restrict__ new_xyzf, int* __restrict__ ballidx)
{
#pragma clang fp contract(off)
    const int gw   = (blockIdx.x * 256 + threadIdx.x) >> 6;   // b*NP + p
    const int lane = threadIdx.x & 63;
    const int b    = gw >> 11;                                 // / NP_
    const float* X = xyz + (size_t)b * N_ * 3;
    const float cx = new_xyzf[(size_t)gw*3];
    const float cy = new_xyzf[(size_t)gw*3+1];
    const float cz = new_xyzf[(size_t)gw*3+2];
    int* outp = ballidx + (size_t)gw * NS_;
    int total = 0, first = -1;
    for (int base = 0; base < N_; base += 64) {
        const int j = base + lane;
        float dx = cx - X[j*3], dy = cy - X[j*3+1], dz = cz - X[j*3+2];
        float d2 = dx*dx;
        d2 = d2 + dy*dy;
        d2 = d2 + dz*dz;
        const bool in = d2 <= R2_;   // f64 threshold semantics of the reference
        ull m = __ballot(in);
        if (m) {
            if (first < 0) first = base + __builtin_ctzll(m);
            int r = total + __popcll(m & ((1ull << lane) - 1ull));
            if (in && r < NS_) outp[r] = j;
            total += (int)__popcll(m);
            if (total >= NS_) break;
        }
    }
    if (total < NS_) {
        int f = first < 0 ? 0 : first;
        if (lane >= total && lane < NS_) outp[lane] = f;
    }
}

// ---------------- layer1: fused gather + GEMM (67->64), uint4 row loads ----------------
__global__ __launch_bounds__(256) void gemm1_kernel(const float* __restrict__ xyz,
    const __hip_bfloat16* __restrict__ featT, const float* __restrict__ newxyz,
    const int* __restrict__ ballidx, const float* __restrict__ W, const float* __restrict__ bias,
    __hip_bfloat16* __restrict__ pre1, float* __restrict__ psum, float* __restrict__ psumsq)
{
    const int lane = threadIdx.x & 63;
    const int gw   = (blockIdx.x * 256 + threadIdx.x) >> 6;   // 4096 waves
    float w[67];
#pragma unroll
    for (int k = 0; k < 67; ++k) w[k] = W[lane*67 + k];
    const float bs = bias[lane];
    float s1 = 0.f, s2 = 0.f;
    for (int r = gw; r < M_; r += 4096) {
        const int b = r >> 16;            // / (NP_*NS_)
        const int p = (r & 65535) >> 5;   // within-batch point
        const int j = ballidx[r];
        const float* xp = xyz    + ((size_t)b*N_  + j)*3;
        const float* cp = newxyz + ((size_t)b*NP_ + p)*3;
        float acc = bs;
        acc = fmaf(xp[0] - cp[0], w[0], acc);
        acc = fmaf(xp[1] - cp[1], w[1], acc);
        acc = fmaf(xp[2] - cp[2], w[2], acc);
        const uint4* rp = (const uint4*)(featT + ((size_t)b*N_ + j)*64);
#pragma unroll
        for (int q = 0; q < 8; ++q) {
            const uint4 u4 = rp[q];
            const unsigned uu0 = u4.x, uu1 = u4.y, uu2 = u4.z, uu3 = u4.w;
            acc = fmaf(__uint_as_float(uu0 << 16),         w[3 + q*8 + 0], acc);
            acc = fmaf(__uint_as_float(uu0 & 0xffff0000u), w[3 + q*8 + 1], acc);
            acc = fmaf(__uint_as_float(uu1 << 16),         w[3 + q*8 + 2], acc);
            acc = fmaf(__uint_as_float(uu1 & 0xffff0000u), w[3 + q*8 + 3], acc);
            acc = fmaf(__uint_as_float(uu2 << 16),         w[3 + q*8 + 4], acc);
            acc = fmaf(__uint_as_float(uu2 & 0xffff0000u), w[3 + q*8 + 5], acc);
            acc = fmaf(__uint_as_float(uu3 << 16),         w[3 + q*8 + 6], acc);
            acc = fmaf(__uint_as_float(uu3 & 0xffff0000u), w[3 + q*8 + 7], acc);
        }
        pre1[(size_t)r*64 + lane] = __float2bfloat16(acc);
        s1 += acc;
        s2 = fmaf(acc, acc, s2);
    }
    psum  [(size_t)gw*64 + lane] = s1;
    psumsq[(size_t)gw*64 + lane] = s2;
}

// ---------------- elementwise BN+ReLU in place on bf16 buffer (one uint4 = 8 elems/thr) ----------
__global__ __launch_bounds__(256) void epi_kernel(__hip_bfloat16* __restrict__ buf,
    const float* __restrict__ sc, const float* __restrict__ sh)
{
    __shared__ float ssc[64], ssh[64];
    if (threadIdx.x < 64) { ssc[threadIdx.x] = sc[threadIdx.x]; ssh[threadIdx.x] = sh[threadIdx.x]; }
    __syncthreads();
    const size_t idx = (size_t)blockIdx.x * 256 + threadIdx.x;   // uint4 index; 8 elems
    const int k0 = (threadIdx.x & 7) * 8;                        // k offset within the 64-ch row
    uint4* p = (uint4*)buf;
    uint4 u = p[idx];
    unsigned wds[4] = {u.x, u.y, u.z, u.w};
    unsigned res[4];
#pragma unroll
    for (int m = 0; m < 4; ++m) {
        const int k = k0 + m*2;
        float v0 = __uint_as_float(wds[m] << 16);
        float v1 = __uint_as_float(wds[m] & 0xffff0000u);
        v0 = fmaxf(fmaf(v0, ssc[k],   ssh[k]),   0.f);
        v1 = fmaxf(fmaf(v1, ssc[k+1], ssh[k+1]), 0.f);
        __hip_bfloat16 b0 = __float2bfloat16(v0);
        __hip_bfloat16 b1 = __float2bfloat16(v1);
        unsigned short s0 = *reinterpret_cast<unsigned short*>(&b0);
        unsigned short s1 = *reinterpret_cast<unsigned short*>(&b1);
        res[m] = (unsigned)s0 | ((unsigned)s1 << 16);
    }
    p[idx] = make_uint4(res[0], res[1], res[2], res[3]);
}

// ---------------- layer2: GEMM 64->64 IN PLACE (input already BN+ReLU'd), uint4 loads ----------
__global__ __launch_bounds__(256) void gemm2_kernel(__hip_bfloat16* __restrict__ buf,
    const float* __restrict__ W, const float* __restrict__ bias,
    float* __restrict__ psum, float* __restrict__ psumsq)
{
    const int lane = threadIdx.x & 63;
    const int gw   = (blockIdx.x * 256 + threadIdx.x) >> 6;   // 4096 waves
    float w[64];
#pragma unroll
    for (int k = 0; k < 64; ++k) w[k] = W[lane*64 + k];
    const float bs = bias[lane];
    float s1 = 0.f, s2 = 0.f;
    for (int r = gw; r < M_; r += 4096) {
        const uint4* rp = (const uint4*)(buf + (size_t)r*64);
        float acc = bs;
#pragma unroll
        for (int q = 0; q < 8; ++q) {
            const uint4 u4 = rp[q];
            const unsigned uu0 = u4.x, uu1 = u4.y, uu2 = u4.z, uu3 = u4.w;
            acc = fmaf(__uint_as_float(uu0 << 16),         w[q*8 + 0], acc);
            acc = fmaf(__uint_as_float(uu0 & 0xffff0000u), w[q*8 + 1], acc);
            acc = fmaf(__uint_as_float(uu1 << 16),         w[q*8 + 2], acc);
            acc = fmaf(__uint_as_float(uu1 & 0xffff0000u), w[q*8 + 3], acc);
            acc = fmaf(__uint_as_float(uu2 << 16),         w[q*8 + 4], acc);
            acc = fmaf(__uint_as_float(uu2 & 0xffff0000u), w[q*8 + 5], acc);
            acc = fmaf(__uint_as_float(uu3 << 16),         w[q*8 + 6], acc);
            acc = fmaf(__uint_as_float(uu3 & 0xffff0000u), w[q*8 + 7], acc);
        }
        buf[(size_t)r*64 + lane] = __float2bfloat16(acc);   // in-place: row read fully above
        s1 += acc;
        s2 = fmaf(acc, acc, s2);
    }
    psum  [(size_t)gw*64 + lane] = s1;
    psumsq[(size_t)gw*64 + lane] = s2;
}

// ---------------- layer3: GEMM 64->128 (input already BN+ReLU'd), max/min fused ----------------
__global__ __launch_bounds__(256) void gemm3_kernel(const __hip_bfloat16* __restrict__ act2,
    const float* __restrict__ W, const float* __restrict__ bias,
    float* __restrict__ mxb, float* __restrict__ mnb,
    float* __restrict__ psum, float* __restrict__ psumsq)
{
    const int lane = threadIdx.x & 63;
    const int gw   = (blockIdx.x * 256 + threadIdx.x) >> 6;   // 16384 waves
    const int pt   = gw >> 1;           // 8192 points
    const int half = gw & 1;
    const int o = half*64 + lane;
    float w[64];
#pragma unroll
    for (int k = 0; k < 64; ++k) w[k] = W[o*64 + k];
    const float bs = bias[o];
    float s1 = 0.f, s2 = 0.f, mx = -1e30f, mn = 1e30f;
    for (int s = 0; s < NS_; ++s) {
        const size_t r = (size_t)pt*NS_ + s;
        const uint4* rp = (const uint4*)(act2 + r*64);
        float acc = bs;
#pragma unroll
        for (int q = 0; q < 8; ++q) {
            const uint4 u4 = rp[q];
            const unsigned uu0 = u4.x, uu1 = u4.y, uu2 = u4.z, uu3 = u4.w;
            acc = fmaf(__uint_as_float(uu0 << 16),         w[q*8 + 0], acc);
            acc = fmaf(__uint_as_float(uu0 & 0xffff0000u), w[q*8 + 1], acc);
            acc = fmaf(__uint_as_float(uu1 << 16),         w[q*8 + 2], acc);
            acc = fmaf(__uint_as_float(uu1 & 0xffff0000u), w[q*8 + 3], acc);
            acc = fmaf(__uint_as_float(uu2 << 16),         w[q*8 + 4], acc);
            acc = fmaf(__uint_as_float(uu2 & 0xffff0000u), w[q*8 + 5], acc);
            acc = fmaf(__uint_as_float(uu3 << 16),         w[q*8 + 6], acc);
            acc = fmaf(__uint_as_float(uu3 & 0xffff0000u), w[q*8 + 7], acc);
        }
        s1 += acc;
        s2 = fmaf(acc, acc, s2);
        mx = fmaxf(mx, acc);
        mn = fminf(mn, acc);
    }
    mxb[(size_t)pt*128 + o] = mx;
    mnb[(size_t)pt*128 + o] = mn;
    psum  [(size_t)pt*128 + o] = s1;
    psumsq[(size_t)pt*128 + o] = s2;
}

// ---------------- deterministic BN stat reduce -> scale/shift ----------------
template<int CO>
__global__ __launch_bounds__(256) void bnred_kernel(const float* __restrict__ psum,
    const float* __restrict__ psumsq, const float* __restrict__ g, const float* __restrict__ beta,
    float* __restrict__ sc, float* __restrict__ sh, int nslots)
{
    const int c = blockIdx.x;
    const int t = threadIdx.x;
    float s1 = 0, s2 = 0;
    for (int i = t; i < nslots; i += 256) {
        s1 += psum  [(size_t)i*CO + c];
        s2 += psumsq[(size_t)i*CO + c];
    }
    __shared__ float a1[256], a2[256];
    a1[t] = s1; a2[t] = s2;
    __syncthreads();
    for (int st = 128; st > 0; st >>= 1) {
        if (t < st) { a1[t] += a1[t+st]; a2[t] += a2[t+st]; }
        __syncthreads();
    }
    if (t == 0) {
        const float invM = 1.0f / (float)M_;
        float mu  = a1[0] * invM;
        float var = fmaxf(a2[0] * invM - mu*mu, 0.f);
        float rs  = 1.0f / sqrtf(var + EPS_);
        float s   = rs * g[c];
        sc[c] = s;
        sh[c] = fmaf(-mu, s, beta[c]);
    }
}

// ---------------- BN3 affine on max/min + ReLU, LDS transpose, write (B,128,NP) f32 ----------------
__global__ __launch_bounds__(256) void final_kernel(const float* __restrict__ mxb,
    const float* __restrict__ mnb, const float* __restrict__ sc, const float* __restrict__ sh,
    float* __restrict__ out)
{
    __shared__ float tile[128][65];
    const int b = blockIdx.y, p0 = blockIdx.x * 64;
    {
        const int o = threadIdx.x & 127, ph = threadIdx.x >> 7;
        const float s = sc[o], h = sh[o];
        const bool pos = (s >= 0.f);
        for (int pl = ph; pl < 64; pl += 2) {
            const size_t pt = (size_t)b*NP_ + p0 + pl;
            float v = pos ? mxb[pt*128 + o] : mnb[pt*128 + o];
            tile[o][pl] = fmaxf(fmaf(v, s, h), 0.f);   // max_s relu(affine) == relu(affine(max/min))
        }
    }
    __syncthreads();
    {
        const int p = threadIdx.x & 63, oh = threadIdx.x >> 6;
        for (int oo = oh; oo < 128; oo += 4)
            out[(size_t)(B_*NP_*3) + ((size_t)(b*128 + oo))*NP_ + p0 + p] = tile[oo][p];
    }
}

// ---------------- launch ----------------
extern "C" void kernel_launch(void* const* d_in, const int* in_sizes, int n_in,
                              void* d_out, int out_size, void* d_ws, size_t ws_size,
                              hipStream_t stream)
{
    const float* xyz  = (const float*)d_in[0];
    const float* feat = (const float*)d_in[1];
    const float* W0   = (const float*)d_in[2];
    const float* b0   = (const float*)d_in[3];
    const float* g0   = (const float*)d_in[4];
    const float* be0  = (const float*)d_in[5];
    const float* W1   = (const float*)d_in[6];
    const float* b1   = (const float*)d_in[7];
    const float* g1   = (const float*)d_in[8];
    const float* be1  = (const float*)d_in[9];
    const float* W2   = (const float*)d_in[10];
    const float* b2   = (const float*)d_in[11];
    const float* g2   = (const float*)d_in[12];
    const float* be2  = (const float*)d_in[13];

    char* ws = (char*)d_ws;                                  // total needed: ~53.1 MB
    float* newxyz = (float*)(ws + 32768);                    //  96 KB
    int*   ball   = (int*)  (ws + 131072);                   //   1 MB
    float* scb    = (float*)(ws + 1179648);                  //   4 KB
    float* psum   = (float*)(ws + 1183744);                  //   4 MB
    float* psumsq = (float*)(ws + 5378048);                  //   4 MB
    __hip_bfloat16* featT = (__hip_bfloat16*)(ws + 9572352); //   4 MB
    float* mxb    = (float*)(ws + 13766656);                 //   4 MB
    float* mnb    = (float*)(ws + 17960960);                 //   4 MB
    __hip_bfloat16* buf1 = (__hip_bfloat16*)(ws + 22155264); //  32 MB (pre1/act1/pre2/act2 in place)
    float* out = (float*)d_out;                              // reference outputs are float32

    float* sc1 = scb;       float* sh1 = scb + 128;
    float* sc2 = scb + 256; float* sh2 = scb + 384;
    float* sc3 = scb + 512; float* sh3 = scb + 640;

    transpose_kernel<<<dim3(N_/64, B_), 256, 0, stream>>>(feat, featT);
    fps_kernel<<<dim3(B_), 512, 0, stream>>>(xyz, newxyz, out);
    ball_kernel<<<dim3(B_*NP_/4), 256, 0, stream>>>(xyz, newxyz, ball);

    gemm1_kernel<<<1024, 256, 0, stream>>>(xyz, featT, newxyz, ball, W0, b0, buf1, psum, psumsq);
    bnred_kernel<64><<<64, 256, 0, stream>>>(psum, psumsq, g0, be0, sc1, sh1, 4096);
    epi_kernel<<<M_*64/8/256, 256, 0, stream>>>(buf1, sc1, sh1);
    gemm2_kernel<<<1024, 256, 0, stream>>>(buf1, W1, b1, psum, psumsq);
    bnred_kernel<64><<<64, 256, 0, stream>>>(psum, psumsq, g1, be1, sc2, sh2, 4096);
    epi_kernel<<<M_*64/8/256, 256, 0, stream>>>(buf1, sc2, sh2);
    gemm3_kernel<<<4096, 256, 0, stream>>>(buf1, W2, b2, mxb, mnb, psum, psumsq);
    bnred_kernel<128><<<128, 256, 0, stream>>>(psum, psumsq, g2, be2, sc3, sh3, 8192);
    final_kernel<<<dim3(NP_/64, B_), 256, 0, stream>>>(mxb, mnb, sc3, sh3, out);
}

// Round 13
// 2315.446 us; speedup vs baseline: 1.1216x; 1.1216x over previous
//
#include <hip/hip_runtime.h>
#include <hip/hip_bf16.h>
#include <cstdint>

#define B_   4
#define N_   8192
#define NP_  2048
#define NS_  32
#define CIN_ 64
#define M_   (B_*NP_*NS_)   // 262144 rows
#define EPS_ 1e-5f
#define R2_  0.01f          // d2 <= 0.01f  <=>  d2 < float64(0.1*0.1)

typedef unsigned long long ull;
typedef float v2f __attribute__((ext_vector_type(2)));

// f32 max with DPP neighbor (invalid lanes keep old value -> identity under max)
template<int CTRL>
__device__ __forceinline__ float dppmaxf(float v)
{
    int o = __builtin_amdgcn_update_dpp(__float_as_int(v), __float_as_int(v), CTRL, 0xF, 0xF, false);
    return fmaxf(v, __int_as_float(o));
}

// ---- fused: blocks 0..3 = FPS (R7 reduction, no in-loop global stores);
//      blocks 4..515 = feature transpose (runs on idle CUs concurrently) ----
__global__ __launch_bounds__(512) void fps_kernel(const float* __restrict__ xyz,
    const float* __restrict__ feat, __hip_bfloat16* __restrict__ featT,
    float* __restrict__ new_xyzf, float* __restrict__ out)
{
#pragma clang fp contract(off)
    __shared__ float4 xyz4[N_];            // 128 KB coords (one b128 read per winner)
    __shared__ unsigned short widxs[NP_];  // 4 KB winner indices
    __shared__ float wavemax[8];
    __shared__ unsigned widx_slot[2];      // parity-buffered winner ~idx
    __shared__ float tile[64][65];         // transpose path (16.6 KB)

    const int t = threadIdx.x;

    if (blockIdx.x >= B_) {
        // ---------- transpose: (B,CIN,N) f32 -> (B,N,CIN) bf16 ----------
        const int blk = blockIdx.x - B_;
        const int b   = blk >> 7;            // / 128
        const int j0  = (blk & 127) * 64;
        const int tx = t & 63, ty = t >> 6;  // 8 row-groups
        for (int cc = ty; cc < 64; cc += 8)
            tile[tx][cc] = feat[((size_t)(b*CIN_ + cc))*N_ + j0 + tx];
        __syncthreads();
        for (int cc = ty; cc < 64; cc += 8)
            featT[((size_t)(b*N_ + j0 + cc))*64 + tx] = __float2bfloat16(tile[cc][tx]);
        return;
    }

    const int b = blockIdx.x;
    const float* X = xyz + (size_t)b * N_ * 3;

    for (int p = t; p < N_; p += 512)
        xyz4[p] = make_float4(X[p*3+0], X[p*3+1], X[p*3+2], 0.f);
    if (t < 2) widx_slot[t] = 0u;
    if (t == 0) widxs[0] = 0;

    // 16 points per thread, strided pairs (2g*512+t, (2g+1)*512+t)  [R7-exact math]
    v2f px[8], py[8], pz[8], dst[8];
#pragma unroll
    for (int g = 0; g < 8; ++g) {
        const int p0 = (2*g)*512 + t, p1 = (2*g+1)*512 + t;
        px[g] = (v2f){X[p0*3+0], X[p1*3+0]};
        py[g] = (v2f){X[p0*3+1], X[p1*3+1]};
        pz[g] = (v2f){X[p0*3+2], X[p1*3+2]};
        dst[g] = (v2f){1e10f, 1e10f};
    }
    const int wv = t >> 6, ln = t & 63;
    float cx = X[0], cy = X[1], cz = X[2];   // first sampled point = index 0

    for (int it = 1; it < NP_; ++it) {
        const int par = it & 1;
        // phase 1: distance update + per-thread best VALUE only
        float bestv = -1.0f;
        const v2f c0 = (v2f){cx, cx}, c1 = (v2f){cy, cy}, c2 = (v2f){cz, cz};
#pragma unroll
        for (int g = 0; g < 8; ++g) {
            v2f dx = px[g] - c0, dy = py[g] - c1, dz = pz[g] - c2;
            v2f dd = dx*dx;          // contract(off): exact numpy op order per component
            dd = dd + dy*dy;
            dd = dd + dz*dz;
            v2f nd;
            nd.x = fminf(dst[g].x, dd.x);
            nd.y = fminf(dst[g].y, dd.y);
            dst[g] = nd;
            bestv = fmaxf(bestv, nd.x);
            bestv = fmaxf(bestv, nd.y);
        }
        // phase 2: wave max via DPP -> LDS slot per wave
        float wm = bestv;
        wm = dppmaxf<0x111>(wm);
        wm = dppmaxf<0x112>(wm);
        wm = dppmaxf<0x114>(wm);
        wm = dppmaxf<0x118>(wm);
        wm = dppmaxf<0x142>(wm);
        wm = dppmaxf<0x143>(wm);
        if (ln == 63) wavemax[wv] = wm;
        __syncthreads();                       // barrier A
        if (t == 0) widx_slot[par ^ 1] = 0u;   // reset other-parity slot (barrier-ordered)
        float bmax = fmaxf(fmaxf(fmaxf(wavemax[0], wavemax[1]), fmaxf(wavemax[2], wavemax[3])),
                           fmaxf(fmaxf(wavemax[4], wavemax[5]), fmaxf(wavemax[6], wavemax[7])));
        // index recovery: only winning thread(s) rescan registers (exec-masked branch)
        if (bestv == bmax) {
            unsigned nin = 0u;
#pragma unroll
            for (int g = 7; g >= 0; --g) {     // descending: last assignment = smallest index
                if (dst[g].y == bmax) nin = ~(unsigned)((2*g+1)*512 + t);
                if (dst[g].x == bmax) nin = ~(unsigned)((2*g)*512 + t);
            }
            atomicMax(&widx_slot[par], nin);   // max ~idx == min idx (numpy tie rule)
        }
        __syncthreads();                       // barrier B
        const int widx = (int)(~widx_slot[par]);
        if (t == 0) widxs[it] = (unsigned short)widx;
        const float4 c = xyz4[widx];           // single b128 broadcast read
        cx = c.x; cy = c.y; cz = c.z;
    }
    __syncthreads();                           // widxs complete
    for (int i = t; i < NP_; i += 512) {       // epilogue: write outputs once
        const float4 c = xyz4[widxs[i]];
        const size_t o3 = ((size_t)(b*NP_ + i)) * 3;
        new_xyzf[o3] = c.x; new_xyzf[o3+1] = c.y; new_xyzf[o3+2] = c.z;
        out[o3] = c.x; out[o3+1] = c.y; out[o3+2] = c.z;
    }
}

// ---------------- ball query: one wave per center ----------------
__global__ __launch_bounds__(256) void ball_kernel(const float* __restrict__ xyz,
    const float* __restrict__ new_xyzf, int* __restrict__ ballidx)
{
#pragma clang fp contract(off)
    const int gw   = (blockIdx.x * 256 + threadIdx.x) >> 6;   // b*NP + p
    const int lane = threadIdx.x & 63;
    const int b    = gw >> 11;                                 // / NP_
    const float* X = xyz + (size_t)b * N_ * 3;
    const float cx = new_xyzf[(size_t)gw*3];
    const float cy = new_xyzf[(size_t)gw*3+1];
    const float cz = new_xyzf[(size_t)gw*3+2];
    int* outp = ballidx + (size_t)gw * NS_;
    int total = 0, first = -1;
    for (int base = 0; base < N_; base += 64) {
        const int j = base + lane;
        float dx = cx - X[j*3], dy = cy - X[j*3+1], dz = cz - X[j*3+2];
        float d2 = dx*dx;
        d2 = d2 + dy*dy;
        d2 = d2 + dz*dz;
        const bool in = d2 <= R2_;   // f64 threshold semantics of the reference
        ull m = __ballot(in);
        if (m) {
            if (first < 0) first = base + __builtin_ctzll(m);
            int r = total + __popcll(m & ((1ull << lane) - 1ull));
            if (in && r < NS_) outp[r] = j;
            total += (int)__popcll(m);
            if (total >= NS_) break;
        }
    }
    if (total < NS_) {
        int f = first < 0 ? 0 : first;
        if (lane >= total && lane < NS_) outp[lane] = f;
    }
}

// ---------------- layer1: fused gather + GEMM (67->64), uint4 row loads ----------------
__global__ __launch_bounds__(256) void gemm1_kernel(const float* __restrict__ xyz,
    const __hip_bfloat16* __restrict__ featT, const float* __restrict__ newxyz,
    const int* __restrict__ ballidx, const float* __restrict__ W, const float* __restrict__ bias,
    __hip_bfloat16* __restrict__ pre1, float* __restrict__ psum, float* __restrict__ psumsq)
{
    const int lane = threadIdx.x & 63;
    const int gw   = (blockIdx.x * 256 + threadIdx.x) >> 6;   // 4096 waves
    float w[67];
#pragma unroll
    for (int k = 0; k < 67; ++k) w[k] = W[lane*67 + k];
    const float bs = bias[lane];
    float s1 = 0.f, s2 = 0.f;
    for (int r = gw; r < M_; r += 4096) {
        const int b = r >> 16;            // / (NP_*NS_)
        const int p = (r & 65535) >> 5;   // within-batch point
        const int j = ballidx[r];
        const float* xp = xyz    + ((size_t)b*N_  + j)*3;
        const float* cp = newxyz + ((size_t)b*NP_ + p)*3;
        float acc = bs;
        acc = fmaf(xp[0] - cp[0], w[0], acc);
        acc = fmaf(xp[1] - cp[1], w[1], acc);
        acc = fmaf(xp[2] - cp[2], w[2], acc);
        const uint4* rp = (const uint4*)(featT + ((size_t)b*N_ + j)*64);
#pragma unroll
        for (int q = 0; q < 8; ++q) {
            const uint4 u4 = rp[q];
            const unsigned uu0 = u4.x, uu1 = u4.y, uu2 = u4.z, uu3 = u4.w;
            acc = fmaf(__uint_as_float(uu0 << 16),         w[3 + q*8 + 0], acc);
            acc = fmaf(__uint_as_float(uu0 & 0xffff0000u), w[3 + q*8 + 1], acc);
            acc = fmaf(__uint_as_float(uu1 << 16),         w[3 + q*8 + 2], acc);
            acc = fmaf(__uint_as_float(uu1 & 0xffff0000u), w[3 + q*8 + 3], acc);
            acc = fmaf(__uint_as_float(uu2 << 16),         w[3 + q*8 + 4], acc);
            acc = fmaf(__uint_as_float(uu2 & 0xffff0000u), w[3 + q*8 + 5], acc);
            acc = fmaf(__uint_as_float(uu3 << 16),         w[3 + q*8 + 6], acc);
            acc = fmaf(__uint_as_float(uu3 & 0xffff0000u), w[3 + q*8 + 7], acc);
        }
        pre1[(size_t)r*64 + lane] = __float2bfloat16(acc);
        s1 += acc;
        s2 = fmaf(acc, acc, s2);
    }
    psum  [(size_t)gw*64 + lane] = s1;
    psumsq[(size_t)gw*64 + lane] = s2;
}

// ---------------- elementwise BN+ReLU in place on bf16 buffer (one uint4 = 8 elems/thr) ----------
__global__ __launch_bounds__(256) void epi_kernel(__hip_bfloat16* __restrict__ buf,
    const float* __restrict__ sc, const float* __restrict__ sh)
{
    __shared__ float ssc[64], ssh[64];
    if (threadIdx.x < 64) { ssc[threadIdx.x] = sc[threadIdx.x]; ssh[threadIdx.x] = sh[threadIdx.x]; }
    __syncthreads();
    const size_t idx = (size_t)blockIdx.x * 256 + threadIdx.x;   // uint4 index; 8 elems
    const int k0 = (threadIdx.x & 7) * 8;                        // k offset within the 64-ch row
    uint4* p = (uint4*)buf;
    uint4 u = p[idx];
    unsigned wds[4] = {u.x, u.y, u.z, u.w};
    unsigned res[4];
#pragma unroll
    for (int m = 0; m < 4; ++m) {
        const int k = k0 + m*2;
        float v0 = __uint_as_float(wds[m] << 16);
        float v1 = __uint_as_float(wds[m] & 0xffff0000u);
        v0 = fmaxf(fmaf(v0, ssc[k],   ssh[k]),   0.f);
        v1 = fmaxf(fmaf(v1, ssc[k+1], ssh[k+1]), 0.f);
        __hip_bfloat16 b0 = __float2bfloat16(v0);
        __hip_bfloat16 b1 = __float2bfloat16(v1);
        unsigned short s0 = *reinterpret_cast<unsigned short*>(&b0);
        unsigned short s1 = *reinterpret_cast<unsigned short*>(&b1);
        res[m] = (unsigned)s0 | ((unsigned)s1 << 16);
    }
    p[idx] = make_uint4(res[0], res[1], res[2], res[3]);
}

// ---------------- layer2: GEMM 64->64 IN PLACE (input already BN+ReLU'd), uint4 loads ----------
__global__ __launch_bounds__(256) void gemm2_kernel(__hip_bfloat16* __restrict__ buf,
    const float* __restrict__ W, const float* __restrict__ bias,
    float* __restrict__ psum, float* __restrict__ psumsq)
{
    const int lane = threadIdx.x & 63;
    const int gw   = (blockIdx.x * 256 + threadIdx.x) >> 6;   // 4096 waves
    float w[64];
#pragma unroll
    for (int k = 0; k < 64; ++k) w[k] = W[lane*64 + k];
    const float bs = bias[lane];
    float s1 = 0.f, s2 = 0.f;
    for (int r = gw; r < M_; r += 4096) {
        const uint4* rp = (const uint4*)(buf + (size_t)r*64);
        float acc = bs;
#pragma unroll
        for (int q = 0; q < 8; ++q) {
            const uint4 u4 = rp[q];
            const unsigned uu0 = u4.x, uu1 = u4.y, uu2 = u4.z, uu3 = u4.w;
            acc = fmaf(__uint_as_float(uu0 << 16),         w[q*8 + 0], acc);
            acc = fmaf(__uint_as_float(uu0 & 0xffff0000u), w[q*8 + 1], acc);
            acc = fmaf(__uint_as_float(uu1 << 16),         w[q*8 + 2], acc);
            acc = fmaf(__uint_as_float(uu1 & 0xffff0000u), w[q*8 + 3], acc);
            acc = fmaf(__uint_as_float(uu2 << 16),         w[q*8 + 4], acc);
            acc = fmaf(__uint_as_float(uu2 & 0xffff0000u), w[q*8 + 5], acc);
            acc = fmaf(__uint_as_float(uu3 << 16),         w[q*8 + 6], acc);
            acc = fmaf(__uint_as_float(uu3 & 0xffff0000u), w[q*8 + 7], acc);
        }
        buf[(size_t)r*64 + lane] = __float2bfloat16(acc);   // in-place: row read fully above
        s1 += acc;
        s2 = fmaf(acc, acc, s2);
    }
    psum  [(size_t)gw*64 + lane] = s1;
    psumsq[(size_t)gw*64 + lane] = s2;
}

// ---------------- layer3: GEMM 64->128 (input already BN+ReLU'd), max/min fused ----------------
__global__ __launch_bounds__(256) void gemm3_kernel(const __hip_bfloat16* __restrict__ act2,
    const float* __restrict__ W, const float* __restrict__ bias,
    float* __restrict__ mxb, float* __restrict__ mnb,
    float* __restrict__ psum, float* __restrict__ psumsq)
{
    const int lane = threadIdx.x & 63;
    const int gw   = (blockIdx.x * 256 + threadIdx.x) >> 6;   // 16384 waves
    const int pt   = gw >> 1;           // 8192 points
    const int half = gw & 1;
    const int o = half*64 + lane;
    float w[64];
#pragma unroll
    for (int k = 0; k < 64; ++k) w[k] = W[o*64 + k];
    const float bs = bias[o];
    float s1 = 0.f, s2 = 0.f, mx = -1e30f, mn = 1e30f;
    for (int s = 0; s < NS_; ++s) {
        const size_t r = (size_t)pt*NS_ + s;
        const uint4* rp = (const uint4*)(act2 + r*64);
        float acc = bs;
#pragma unroll
        for (int q = 0; q < 8; ++q) {
            const uint4 u4 = rp[q];
            const unsigned uu0 = u4.x, uu1 = u4.y, uu2 = u4.z, uu3 = u4.w;
            acc = fmaf(__uint_as_float(uu0 << 16),         w[q*8 + 0], acc);
            acc = fmaf(__uint_as_float(uu0 & 0xffff0000u), w[q*8 + 1], acc);
            acc = fmaf(__uint_as_float(uu1 << 16),         w[q*8 + 2], acc);
            acc = fmaf(__uint_as_float(uu1 & 0xffff0000u), w[q*8 + 3], acc);
            acc = fmaf(__uint_as_float(uu2 << 16),         w[q*8 + 4], acc);
            acc = fmaf(__uint_as_float(uu2 & 0xffff0000u), w[q*8 + 5], acc);
            acc = fmaf(__uint_as_float(uu3 << 16),         w[q*8 + 6], acc);
            acc = fmaf(__uint_as_float(uu3 & 0xffff0000u), w[q*8 + 7], acc);
        }
        s1 += acc;
        s2 = fmaf(acc, acc, s2);
        mx = fmaxf(mx, acc);
        mn = fminf(mn, acc);
    }
    mxb[(size_t)pt*128 + o] = mx;
    mnb[(size_t)pt*128 + o] = mn;
    psum  [(size_t)pt*128 + o] = s1;
    psumsq[(size_t)pt*128 + o] = s2;
}

// ---------------- deterministic BN stat reduce -> scale/shift ----------------
template<int CO>
__global__ __launch_bounds__(256) void bnred_kernel(const float* __restrict__ psum,
    const float* __restrict__ psumsq, const float* __restrict__ g, const float* __restrict__ beta,
    float* __restrict__ sc, float* __restrict__ sh, int nslots)
{
    const int c = blockIdx.x;
    const int t = threadIdx.x;
    float s1 = 0, s2 = 0;
    for (int i = t; i < nslots; i += 256) {
        s1 += psum  [(size_t)i*CO + c];
        s2 += psumsq[(size_t)i*CO + c];
    }
    __shared__ float a1[256], a2[256];
    a1[t] = s1; a2[t] = s2;
    __syncthreads();
    for (int st = 128; st > 0; st >>= 1) {
        if (t < st) { a1[t] += a1[t+st]; a2[t] += a2[t+st]; }
        __syncthreads();
    }
    if (t == 0) {
        const float invM = 1.0f / (float)M_;
        float mu  = a1[0] * invM;
        float var = fmaxf(a2[0] * invM - mu*mu, 0.f);
        float rs  = 1.0f / sqrtf(var + EPS_);
        float s   = rs * g[c];
        sc[c] = s;
        sh[c] = fmaf(-mu, s, beta[c]);
    }
}

// ---------------- BN3 affine on max/min + ReLU, LDS transpose, write (B,128,NP) f32 ----------------
__global__ __launch_bounds__(256) void final_kernel(const float* __restrict__ mxb,
    const float* __restrict__ mnb, const float* __restrict__ sc, const float* __restrict__ sh,
    float* __restrict__ out)
{
    __shared__ float tile[128][65];
    const int b = blockIdx.y, p0 = blockIdx.x * 64;
    {
        const int o = threadIdx.x & 127, ph = threadIdx.x >> 7;
        const float s = sc[o], h = sh[o];
        const bool pos = (s >= 0.f);
        for (int pl = ph; pl < 64; pl += 2) {
            const size_t pt = (size_t)b*NP_ + p0 + pl;
            float v = pos ? mxb[pt*128 + o] : mnb[pt*128 + o];
            tile[o][pl] = fmaxf(fmaf(v, s, h), 0.f);   // max_s relu(affine) == relu(affine(max/min))
        }
    }
    __syncthreads();
    {
        const int p = threadIdx.x & 63, oh = threadIdx.x >> 6;
        for (int oo = oh; oo < 128; oo += 4)
            out[(size_t)(B_*NP_*3) + ((size_t)(b*128 + oo))*NP_ + p0 + p] = tile[oo][p];
    }
}

// ---------------- launch ----------------
extern "C" void kernel_launch(void* const* d_in, const int* in_sizes, int n_in,
                              void* d_out, int out_size, void* d_ws, size_t ws_size,
                              hipStream_t stream)
{
    const float* xyz  = (const float*)d_in[0];
    const float* feat = (const float*)d_in[1];
    const float* W0   = (const float*)d_in[2];
    const float* b0   = (const float*)d_in[3];
    const float* g0   = (const float*)d_in[4];
    const float* be0  = (const float*)d_in[5];
    const float* W1   = (const float*)d_in[6];
    const float* b1   = (const float*)d_in[7];
    const float* g1   = (const float*)d_in[8];
    const float* be1  = (const float*)d_in[9];
    const float* W2   = (const float*)d_in[10];
    const float* b2   = (const float*)d_in[11];
    const float* g2   = (const float*)d_in[12];
    const float* be2  = (const float*)d_in[13];

    char* ws = (char*)d_ws;                                  // total needed: ~53.1 MB
    float* newxyz = (float*)(ws + 32768);                    //  96 KB
    int*   ball   = (int*)  (ws + 131072);                   //   1 MB
    float* scb    = (float*)(ws + 1179648);                  //   4 KB
    float* psum   = (float*)(ws + 1183744);                  //   4 MB
    float* psumsq = (float*)(ws + 5378048);                  //   4 MB
    __hip_bfloat16* featT = (__hip_bfloat16*)(ws + 9572352); //   4 MB
    float* mxb    = (float*)(ws + 13766656);                 //   4 MB
    float* mnb    = (float*)(ws + 17960960);                 //   4 MB
    __hip_bfloat16* buf1 = (__hip_bfloat16*)(ws + 22155264); //  32 MB (pre1/act1/pre2/act2 in place)
    float* out = (float*)d_out;                              // reference outputs are float32

    float* sc1 = scb;       float* sh1 = scb + 128;
    float* sc2 = scb + 256; float* sh2 = scb + 384;
    float* sc3 = scb + 512; float* sh3 = scb + 640;

    // blocks 0..3: FPS; blocks 4..515: feature transpose (concurrent on idle CUs)
    fps_kernel<<<dim3(B_ + B_*(N_/64)), 512, 0, stream>>>(xyz, feat, featT, newxyz, out);
    ball_kernel<<<dim3(B_*NP_/4), 256, 0, stream>>>(xyz, newxyz, ball);

    gemm1_kernel<<<1024, 256, 0, stream>>>(xyz, featT, newxyz, ball, W0, b0, buf1, psum, psumsq);
    bnred_kernel<64><<<64, 256, 0, stream>>>(psum, psumsq, g0, be0, sc1, sh1, 4096);
    epi_kernel<<<M_*64/8/256, 256, 0, stream>>>(buf1, sc1, sh1);
    gemm2_kernel<<<1024, 256, 0, stream>>>(buf1, W1, b1, psum, psumsq);
    bnred_kernel<64><<<64, 256, 0, stream>>>(psum, psumsq, g1, be1, sc2, sh2, 4096);
    epi_kernel<<<M_*64/8/256, 256, 0, stream>>>(buf1, sc2, sh2);
    gemm3_kernel<<<4096, 256, 0, stream>>>(buf1, W2, b2, mxb, mnb, psum, psumsq);
    bnred_kernel<128><<<128, 256, 0, stream>>>(psum, psumsq, g2, be2, sc3, sh3, 8192);
    final_kernel<<<dim3(NP_/64, B_), 256, 0, stream>>>(mxb, mnb, sc3, sh3, out);
}